// Round 3
// baseline (295.076 us; speedup 1.0000x reference)
//
#include <hip/hip_runtime.h>
#include <hip/hip_bf16.h>

#define NN 50000      // nodes
#define NE 800000     // edges
#define NR 500        // relations
#define KEH 256       // input feat dim
#define KRH 128       // proj feat dim
#define NSB 8         // node super-bins (node / 6250), aligned to 8 XCDs
#define SBW 6250      // super-bin width
#define NBK (NR*NSB)  // 4000 buckets
#define NBE 256       // edge-pass blocks (k_edge / k_mkrec)
#define EPB (NE/NBE)  // 3125 edges per block
#define NTILE 3125    // 16-row GEMM tiles (50000/16 exactly)

typedef __attribute__((ext_vector_type(8))) __bf16 bf16x8;
typedef __attribute__((ext_vector_type(4))) float f32x4;

// ---- workspace layout (bytes, 16B aligned), total ~63.4 MiB ----
#define OFF_XH     0UL            // [NN][128] bf16
#define OFF_XT     12800000UL     // [NN][128] bf16
#define OFF_SP     25600000UL     // [NN] float4
#define OFF_DP     26400000UL     // [NN] float4
#define OFF_SUMS   27200000UL     // [NR*4] f32 (8000 B)
#define OFF_HISTH  27208000UL     // [NBK] u32 totals (16000 B)
#define OFF_HISTT  27224000UL     // [NBK] u32 totals (16000 B)
// zero region SUMS..HISTT = 40000 B = 10000 u32
#define OFF_INVS   27240000UL     // [NR*4] f32
#define OFF_BASEH  27248000UL     // [NBK+1] u32 (16016 B)
#define OFF_BASET  27264016UL     // [NBK+1] u32
#define OFF_RECH   27312032UL     // [NE] uint2 (node, w1) 6.4 MB
#define OFF_RECT   33712032UL     // [NE] uint2 (node, w2) 6.4 MB
#define OFF_PART   40112032UL     // [NBK][128] f32 partials (2.048 MB)
#define OFF_AH     42160032UL     // [256] f32
#define OFF_AT     42161056UL     // [256] f32
#define OFF_FLAG   42162080UL     // u32
#define OFF_WHH    42162144UL     // [128][256] bf16, FRAGMENT order
#define OFF_WHL    42227680UL
#define OFF_WTH    42293216UL
#define OFF_WTL    42358752UL
#define OFF_HPBH   42424288UL     // [NBE][NBK] u32 per-block hist/offsets 4.096 MB
#define OFF_HPBT   46520288UL     // [NBE][NBK] u32                       4.096 MB
#define OFF_EX     50616288UL     // [NE] float4 exp-scores 12.8 MB
// end 63,416,288

__device__ __forceinline__ int clampi(int v, int hi) {  // [0, hi)
    v = v < 0 ? 0 : v;
    return v >= hi ? hi - 1 : v;
}

// Wave-replicated dtype sniff (see round-8 notes).
__device__ __forceinline__ int sniff_isbf(const unsigned* xe_raw) {
    int lane = threadIdx.x & 63;
    unsigned w = xe_raw[lane];
    unsigned ex = (w >> 7) & 0xFFu;
    bool hit = (ex >= 115u && ex <= 131u);
    return __popcll(__ballot(hit)) >= 32;
}

// block 0: flag + a_h/a_t convert. blocks 1..128: weight split -> FRAGMENT
// order (see k_gemm). blocks 129+: zero sums + histH + histT (10000 u32).
// Frag order: out index o = ((ct*8+ks)*64 + q*16 + c)*8 + e  holds
// w[ct*16+c][ks*32+q*8+e]  — so lane l=q*16+c of fragment (ct,ks) reads its
// 8 contiguous bf16 (col=l&15, k-seg=(l>>4)*8) as one 16B chunk, and a
// wave's fragment read is one contiguous 1KB global_load_dwordx4.
__global__ __launch_bounds__(256) void k_init(const unsigned* __restrict__ xe_raw,
                                              const void* __restrict__ ah_in, const void* __restrict__ at_in,
                                              const void* __restrict__ wh, const void* __restrict__ wt,
                                              unsigned* __restrict__ flag, float* __restrict__ ah32,
                                              float* __restrict__ at32,
                                              __bf16* __restrict__ whh, __bf16* __restrict__ whl,
                                              __bf16* __restrict__ wth, __bf16* __restrict__ wtl,
                                              unsigned* __restrict__ zero1) {
    int isbf = sniff_isbf(xe_raw);
    int t = threadIdx.x;
    if (blockIdx.x == 0) {
        if (t == 0) flag[0] = (unsigned)isbf;
        ah32[t] = isbf ? __bfloat162float(((const __hip_bfloat16*)ah_in)[t]) : ((const float*)ah_in)[t];
        at32[t] = isbf ? __bfloat162float(((const __hip_bfloat16*)at_in)[t]) : ((const float*)at_in)[t];
    } else if (blockIdx.x <= 128) {
        int o = (blockIdx.x - 1) * 256 + t;   // [0, 32768) frag-order output idx
        int e = o & 7, c = (o >> 3) & 15, q = (o >> 7) & 3, ks = (o >> 9) & 7, ct = o >> 12;
        int i = (ct * 16 + c) * KEH + ks * 32 + q * 8 + e;   // row-major source
        if (isbf) {
            whh[o] = ((const __bf16*)wh)[i]; whl[o] = (__bf16)0.f;
            wth[o] = ((const __bf16*)wt)[i]; wtl[o] = (__bf16)0.f;
        } else {
            float a = ((const float*)wh)[i];
            float b = ((const float*)wt)[i];
            __bf16 ah_ = (__bf16)a, bh_ = (__bf16)b;
            whh[o] = ah_; whl[o] = (__bf16)(a - (float)ah_);
            wth[o] = bh_; wtl[o] = (__bf16)(b - (float)bh_);
        }
    } else {
        int stride = (gridDim.x - 129) * 256;
        for (int i = (blockIdx.x - 129) * 256 + t; i < 10000; i += stride) zero1[i] = 0u;
    }
}

// LDS-free, barrier-free GEMM + fused per-node scores.
// Wave-job j in [0, 2*NTILE): tile = j>>1, phase = j&1 (0=H->xh, 1=T->xt).
// Each wave: 8 A-frag loads (16 rows from HBM), 64 B-frag loads (1KB each,
// contiguous, L2-resident frag-order weights), 64 MFMAs, then epilogue:
// xh/xt stores + 4 score dot-products per row via 16-lane shfl_xor reduce,
// half-written to sp/dp (phases write disjoint float2 halves).
// Grid 1563x256: the two phase-waves of a tile share a block -> A hits L1.
__global__ __launch_bounds__(256) void k_gemm(const void* __restrict__ xe,
                                              const unsigned* __restrict__ flag,
                                              const __bf16* __restrict__ whh, const __bf16* __restrict__ whl,
                                              const __bf16* __restrict__ wth, const __bf16* __restrict__ wtl,
                                              const float* __restrict__ ah, const float* __restrict__ at,
                                              __hip_bfloat16* __restrict__ xh, __hip_bfloat16* __restrict__ xt,
                                              float2* __restrict__ sp2, float2* __restrict__ dp2) {
    const int t = threadIdx.x, lane = t & 63, wave = t >> 6;
    const int l16 = lane & 15, quad = lane >> 4;
    const int j = blockIdx.x * 4 + wave;
    if (j >= 2 * NTILE) return;
    const int tile = j >> 1, ph = j & 1;
    const int row = tile * 16 + l16;           // this lane's A row
    const int isbf = (int)flag[0];
    const __bf16* wfh = ph ? wth : whh;        // frag-order weights (hi)

    f32x4 acc[8];
    #pragma unroll
    for (int ct = 0; ct < 8; ++ct) acc[ct] = (f32x4){0.f, 0.f, 0.f, 0.f};

    if (isbf) {
        const __bf16* xb = (const __bf16*)xe + (size_t)row * KEH;
        bf16x8 a[8];
        #pragma unroll
        for (int ks = 0; ks < 8; ++ks)
            a[ks] = *(const bf16x8*)(xb + ks * 32 + quad * 8);
        #pragma unroll
        for (int ks = 0; ks < 8; ++ks)
            #pragma unroll
            for (int ct = 0; ct < 8; ++ct)
                acc[ct] = __builtin_amdgcn_mfma_f32_16x16x32_bf16(
                    a[ks], *(const bf16x8*)(wfh + (((ct * 8 + ks) * 64 + lane) << 3)),
                    acc[ct], 0, 0, 0);
    } else {
        // fp32 compat path: error-compensated bf16 split, 3 MFMAs per frag.
        const __bf16* wfl = ph ? wtl : whl;
        const float* xf = (const float*)xe + (size_t)row * KEH;
        bf16x8 ahi[8], alo[8];
        #pragma unroll
        for (int ks = 0; ks < 8; ++ks) {
            const float* p = xf + ks * 32 + quad * 8;
            float4 u0 = *(const float4*)p, u1 = *(const float4*)(p + 4);
            float v[8] = {u0.x,u0.y,u0.z,u0.w,u1.x,u1.y,u1.z,u1.w};
            #pragma unroll
            for (int jj = 0; jj < 8; ++jj) {
                __bf16 hi = (__bf16)v[jj];
                ahi[ks][jj] = hi;
                alo[ks][jj] = (__bf16)(v[jj] - (float)hi);
            }
        }
        #pragma unroll
        for (int ks = 0; ks < 8; ++ks)
            #pragma unroll
            for (int ct = 0; ct < 8; ++ct) {
                int fo = ((ct * 8 + ks) * 64 + lane) << 3;
                bf16x8 bh = *(const bf16x8*)(wfh + fo);
                bf16x8 bl = *(const bf16x8*)(wfl + fo);
                acc[ct] = __builtin_amdgcn_mfma_f32_16x16x32_bf16(ahi[ks], bh, acc[ct], 0, 0, 0);
                acc[ct] = __builtin_amdgcn_mfma_f32_16x16x32_bf16(alo[ks], bh, acc[ct], 0, 0, 0);
                acc[ct] = __builtin_amdgcn_mfma_f32_16x16x32_bf16(ahi[ks], bl, acc[ct], 0, 0, 0);
            }
    }

    // ---- epilogue: store projected rows + fused scores ----
    __hip_bfloat16* out = ph ? xt : xh;
    float s0[4] = {0.f,0.f,0.f,0.f}, s1[4] = {0.f,0.f,0.f,0.f};
    float s2[4] = {0.f,0.f,0.f,0.f}, s3[4] = {0.f,0.f,0.f,0.f};
    #pragma unroll
    for (int ct = 0; ct < 8; ++ct) {
        int c = ct * 16 + l16;
        float va0 = ah[c], va1 = ah[128 + c];
        float vb0 = at[c], vb1 = at[128 + c];
        #pragma unroll
        for (int jj = 0; jj < 4; ++jj) {
            float v = acc[ct][jj];
            s0[jj] = fmaf(v, va0, s0[jj]);
            s1[jj] = fmaf(v, va1, s1[jj]);
            s2[jj] = fmaf(v, vb0, s2[jj]);
            s3[jj] = fmaf(v, vb1, s3[jj]);
            out[(size_t)(tile * 16 + quad * 4 + jj) * KRH + c] = __float2bfloat16(v);
        }
    }
    #pragma unroll
    for (int off = 8; off; off >>= 1)
        #pragma unroll
        for (int jj = 0; jj < 4; ++jj) {
            s0[jj] += __shfl_xor(s0[jj], off);
            s1[jj] += __shfl_xor(s1[jj], off);
            s2[jj] += __shfl_xor(s2[jj], off);
            s3[jj] += __shfl_xor(s3[jj], off);
        }
    if (l16 == 0) {
        // sp = (s_hh0, s_hh1, s_th0, s_th1); dp = (s_tt0, s_tt1, s_ht0, s_ht1)
        #pragma unroll
        for (int jj = 0; jj < 4; ++jj) {
            int n = tile * 16 + quad * 4 + jj;
            if (ph == 0) {
                sp2[n * 2 + 0] = make_float2(s0[jj], s1[jj]);   // s_hh
                dp2[n * 2 + 1] = make_float2(s2[jj], s3[jj]);   // s_ht
            } else {
                sp2[n * 2 + 1] = make_float2(s0[jj], s1[jj]);   // s_th
                dp2[n * 2 + 0] = make_float2(s2[jj], s3[jj]);   // s_tt
            }
        }
    }
}

__device__ __forceinline__ float eexp(float x) {
    x = x > 0.f ? x : 0.01f * x;
    x = fminf(x, 50.f);
    return __expf(x);
}

// Per edge (contiguous 3125-edge range per block, 1024 thr = 16 waves/CU):
// 4 exp scores -> ex4 store + LDS segment sums + (rel,sbin) histograms ->
// global totals (atomic) AND this block's private hpb row (non-atomic).
__global__ __launch_bounds__(1024) void k_edge(const int* __restrict__ src, const int* __restrict__ dst,
                                               const int* __restrict__ rel,
                                               const float4* __restrict__ sp, const float4* __restrict__ dp,
                                               float* __restrict__ sums,
                                               unsigned* __restrict__ histH, unsigned* __restrict__ histT,
                                               unsigned* __restrict__ hpbH, unsigned* __restrict__ hpbT,
                                               float4* __restrict__ ex4) {
    __shared__ float ls[NR * 4];
    __shared__ unsigned lhH[NBK], lhT[NBK];
    int t = threadIdx.x;
    for (int i = t; i < NR * 4; i += 1024) ls[i] = 0.f;
    for (int i = t; i < NBK; i += 1024) { lhH[i] = 0u; lhT[i] = 0u; }
    __syncthreads();
    unsigned lo = blockIdx.x * EPB, hi = lo + EPB;
    for (unsigned e = lo + t; e < hi; e += 1024) {
        int s = clampi(src[e], NN), d = clampi(dst[e], NN), r = clampi(rel[e], NR);
        float4 a = sp[s], b = dp[d];
        float4 ex;
        ex.x = eexp(a.x + b.x); ex.y = eexp(a.y + b.y);
        ex.z = eexp(a.z + b.z); ex.w = eexp(a.w + b.w);
        ex4[e] = ex;
        atomicAdd(&ls[r*4+0], ex.x);
        atomicAdd(&ls[r*4+1], ex.y);
        atomicAdd(&ls[r*4+2], ex.z);
        atomicAdd(&ls[r*4+3], ex.w);
        atomicAdd(&lhH[r * NSB + s / SBW], 1u);
        atomicAdd(&lhT[r * NSB + d / SBW], 1u);
    }
    __syncthreads();
    for (int i = t; i < NR * 4; i += 1024)
        if (ls[i] != 0.f) atomicAdd(&sums[i], ls[i]);
    size_t row = (size_t)blockIdx.x * NBK;
    for (int i = t; i < NBK; i += 1024) {
        unsigned cH = lhH[i], cT = lhT[i];
        hpbH[row + i] = cH;
        hpbT[row + i] = cT;
        if (cH) atomicAdd(&histH[i], cH);
        if (cT) atomicAdd(&histT[i], cT);
    }
}

// Scan both 4000-bin total histograms -> bucket bases; invs = 1/(sums+eps).
__global__ __launch_bounds__(1024) void k_scan2(const unsigned* __restrict__ histH,
                                                const unsigned* __restrict__ histT,
                                                const float* __restrict__ sums,
                                                unsigned* __restrict__ baseH, unsigned* __restrict__ baseT,
                                                float* __restrict__ invs) {
    __shared__ unsigned sc[1024];
    int t = threadIdx.x;
    for (int pass = 0; pass < 2; ++pass) {
        const unsigned* h = pass ? histT : histH;
        unsigned* base = pass ? baseT : baseH;
        int j0 = t * 4;
        unsigned v[4], s = 0;
        for (int k = 0; k < 4; ++k) { v[k] = (j0 + k < NBK) ? h[j0 + k] : 0u; s += v[k]; }
        sc[t] = s;
        __syncthreads();
        for (int off = 1; off < 1024; off <<= 1) {
            unsigned add = (t >= off) ? sc[t - off] : 0u;
            __syncthreads();
            sc[t] += add;
            __syncthreads();
        }
        unsigned run = sc[t] - s;
        for (int k = 0; k < 4; ++k) {
            if (j0 + k < NBK) { base[j0 + k] = run; run += v[k]; }
        }
        if (t == 1023) base[NBK] = sc[1023];
        __syncthreads();
    }
    for (int i = t; i < NR * 4; i += 1024) invs[i] = 1.f / (sums[i] + 1e-16f);
}

// Column scan: per (pass,bin), exclusive-scan the NBE per-block counts and add
// the bucket base -> hpb becomes each block's exact write offset. No atomics.
__global__ __launch_bounds__(NBE) void k_colscan(unsigned* __restrict__ hpbH, unsigned* __restrict__ hpbT,
                                                 const unsigned* __restrict__ baseH,
                                                 const unsigned* __restrict__ baseT) {
    __shared__ unsigned sc[NBE];
    int b = blockIdx.x;              // [0, 2*NBK)
    int pass = b >= NBK;
    int bin = pass ? b - NBK : b;
    unsigned* h = pass ? hpbT : hpbH;
    unsigned basev = (pass ? baseT : baseH)[bin];
    int t = threadIdx.x;
    unsigned v = h[(size_t)t * NBK + bin];
    sc[t] = v;
    __syncthreads();
    for (int off = 1; off < NBE; off <<= 1) {
        unsigned add = (t >= off) ? sc[t - off] : 0u;
        __syncthreads();
        sc[t] += add;
        __syncthreads();
    }
    h[(size_t)t * NBK + bin] = basev + sc[t] - v;
}

// Single-pass scatter (1024 thr): weights from streamed ex4 (no gathers, no
// exp); LDS cursors from precomputed per-block offsets.
__global__ __launch_bounds__(1024) void k_mkrec(const int* __restrict__ src, const int* __restrict__ dst,
                                                const int* __restrict__ rel,
                                                const float4* __restrict__ ex4,
                                                const float4* __restrict__ invs4,
                                                const unsigned* __restrict__ hpbH, const unsigned* __restrict__ hpbT,
                                                uint2* __restrict__ recH, uint2* __restrict__ recT) {
    __shared__ unsigned lcH[NBK], lcT[NBK];
    int t = threadIdx.x;
    size_t row = (size_t)blockIdx.x * NBK;
    for (int i = t; i < NBK; i += 1024) { lcH[i] = hpbH[row + i]; lcT[i] = hpbT[row + i]; }
    __syncthreads();
    unsigned lo = blockIdx.x * EPB, hi = lo + EPB;
    for (unsigned e = lo + t; e < hi; e += 1024) {
        int s = clampi(src[e], NN), d = clampi(dst[e], NN), r = clampi(rel[e], NR);
        float4 ex = ex4[e];
        float4 iv = invs4[r];
        float w1 = ex.x * iv.x + ex.y * iv.y;
        float w2 = ex.z * iv.z + ex.w * iv.w;
        unsigned pH = atomicAdd(&lcH[r * NSB + s / SBW], 1u);
        unsigned pT = atomicAdd(&lcT[r * NSB + d / SBW], 1u);
        if (pH < NE) recH[pH] = make_uint2((unsigned)s, __float_as_uint(w1));
        if (pT < NE) recT[pT] = make_uint2((unsigned)d, __float_as_uint(w2));
    }
}

// One block per (rel,sbin) bucket. Chunked: stage 256 recs into LDS in one
// coalesced burst, then each wave runs an 8-wide gather unroll with rec reads
// from LDS — rec-load latency off the critical path, 8 gathers in flight.
__global__ __launch_bounds__(256) void k_accR(const uint2* __restrict__ recH, const uint2* __restrict__ recT,
                                              const unsigned* __restrict__ baseH, const unsigned* __restrict__ baseT,
                                              const __hip_bfloat16* __restrict__ xh,
                                              const __hip_bfloat16* __restrict__ xt,
                                              float* __restrict__ part) {
    __shared__ float red[4][128];
    __shared__ uint2 lrec[256];
    int b = blockIdx.x;
    int t = threadIdx.x, lane = t & 63, wv = t >> 6;
    int c2 = lane * 2;
    float ax = 0.f, ay = 0.f;
    for (int pass = 0; pass < 2; ++pass) {
        const uint2* rec = pass ? recT : recH;
        const unsigned* base = pass ? baseT : baseH;
        const unsigned short* xs = (const unsigned short*)(pass ? xt : xh);
        unsigned b0 = base[b];
        unsigned cnt = base[b + 1] - b0;
        if (cnt > NE) cnt = 0;        // poison guard
        for (unsigned cb = 0; cb < cnt; cb += 256u) {
            unsigned cn = cnt - cb; if (cn > 256u) cn = 256u;
            __syncthreads();                       // prior chunk readers done
            if ((unsigned)t < cn) lrec[t] = rec[b0 + cb + t];
            __syncthreads();
            for (unsigned j = (unsigned)wv; j < cn; j += 32) {
                unsigned nd[8]; float w[8];
                #pragma unroll
                for (int k = 0; k < 8; ++k) {
                    unsigned jj = j + 4u * k;
                    bool m = jj < cn;
                    uint2 v = lrec[m ? jj : j];
                    nd[k] = v.x < NN ? v.x : 0u;
                    w[k] = m ? __uint_as_float(v.y) : 0.f;
                }
                unsigned u[8];
                #pragma unroll
                for (int k = 0; k < 8; ++k)
                    u[k] = *(const unsigned*)(xs + (size_t)nd[k] * KRH + c2);
                #pragma unroll
                for (int k = 0; k < 8; ++k) {
                    ax = fmaf(w[k], __uint_as_float(u[k] << 16), ax);
                    ay = fmaf(w[k], __uint_as_float(u[k] & 0xffff0000u), ay);
                }
            }
        }
    }
    __syncthreads();
    red[wv][c2] = ax; red[wv][c2 + 1] = ay;
    __syncthreads();
    if (wv == 0) {
        float vx = red[0][c2] + red[1][c2] + red[2][c2] + red[3][c2];
        float vy = red[0][c2+1] + red[1][c2+1] + red[2][c2+1] + red[3][c2+1];
        *(float2*)(&part[(size_t)b * KRH + c2]) = make_float2(vx, vy);
    }
}

// out[r][c] = 0.25 * sum_sbin part[r*8+sbin][c]; dtype follows input.
__global__ __launch_bounds__(256) void k_out(const float* __restrict__ part,
                                             const unsigned* __restrict__ flag, void* __restrict__ out) {
    int i = blockIdx.x * 256 + threadIdx.x;
    if (i < NR * KRH) {
        int r = i >> 7, c = i & 127;
        float v = 0.f;
        for (int s = 0; s < NSB; ++s) v += part[(size_t)(r * NSB + s) * KRH + c];
        v *= 0.25f;                   // / num_heads(2) / 2
        if (!isfinite(v)) v = 0.f;
        if (flag[0]) ((__hip_bfloat16*)out)[i] = __float2bfloat16(v);
        else         ((float*)out)[i] = v;
    }
}

extern "C" void kernel_launch(void* const* d_in, const int* in_sizes, int n_in,
                              void* d_out, int out_size, void* d_ws, size_t ws_size,
                              hipStream_t stream) {
    const void* xe  = d_in[0];
    const int* eidx = (const int*)d_in[1];
    const int* rel  = (const int*)d_in[2];
    const void* wh  = d_in[3];
    const void* wt  = d_in[4];
    const void* ahp = d_in[5];
    const void* atp = d_in[6];

    const int* src = eidx;
    const int* dst = eidx + NE;

    char* ws = (char*)d_ws;
    __hip_bfloat16* xh = (__hip_bfloat16*)(ws + OFF_XH);
    __hip_bfloat16* xt = (__hip_bfloat16*)(ws + OFF_XT);
    float4*   sp     = (float4*)(ws + OFF_SP);
    float4*   dp     = (float4*)(ws + OFF_DP);
    float*    sums   = (float*)(ws + OFF_SUMS);
    unsigned* histH  = (unsigned*)(ws + OFF_HISTH);
    unsigned* histT  = (unsigned*)(ws + OFF_HISTT);
    float*    invs   = (float*)(ws + OFF_INVS);
    unsigned* baseH  = (unsigned*)(ws + OFF_BASEH);
    unsigned* baseT  = (unsigned*)(ws + OFF_BASET);
    uint2*    recH   = (uint2*)(ws + OFF_RECH);
    uint2*    recT   = (uint2*)(ws + OFF_RECT);
    float*    partp  = (float*)(ws + OFF_PART);
    float*    ah32   = (float*)(ws + OFF_AH);
    float*    at32   = (float*)(ws + OFF_AT);
    unsigned* flag   = (unsigned*)(ws + OFF_FLAG);
    __bf16*   whh    = (__bf16*)(ws + OFF_WHH);
    __bf16*   whl    = (__bf16*)(ws + OFF_WHL);
    __bf16*   wth    = (__bf16*)(ws + OFF_WTH);
    __bf16*   wtl    = (__bf16*)(ws + OFF_WTL);
    unsigned* hpbH   = (unsigned*)(ws + OFF_HPBH);
    unsigned* hpbT   = (unsigned*)(ws + OFF_HPBT);
    float4*   ex4    = (float4*)(ws + OFF_EX);

    k_init<<<161, 256, 0, stream>>>((const unsigned*)xe, ahp, atp, wh, wt, flag, ah32, at32,
                                     whh, whl, wth, wtl, (unsigned*)(ws + OFF_SUMS));
    k_gemm<<<(2 * NTILE + 3) / 4, 256, 0, stream>>>(xe, flag, whh, whl, wth, wtl, ah32, at32,
                                                    xh, xt, (float2*)sp, (float2*)dp);
    k_edge<<<NBE, 1024, 0, stream>>>(src, dst, rel, sp, dp, sums, histH, histT, hpbH, hpbT, ex4);
    k_scan2<<<1, 1024, 0, stream>>>(histH, histT, sums, baseH, baseT, invs);
    k_colscan<<<2 * NBK, NBE, 0, stream>>>(hpbH, hpbT, baseH, baseT);
    k_mkrec<<<NBE, 1024, 0, stream>>>(src, dst, rel, ex4, (const float4*)invs, hpbH, hpbT, recH, recT);
    k_accR<<<NBK, 256, 0, stream>>>(recH, recT, baseH, baseT, xh, xt, partp);
    k_out<<<(NR * KRH + 255) / 256, 256, 0, stream>>>(partp, flag, d_out);
}

// Round 4
// 277.462 us; speedup vs baseline: 1.0635x; 1.0635x over previous
//
#include <hip/hip_runtime.h>
#include <hip/hip_bf16.h>

#define NN 50000      // nodes
#define NE 800000     // edges
#define NR 500        // relations
#define KEH 256       // input feat dim
#define KRH 128       // proj feat dim
#define NSB 8         // node super-bins (node / 6250), aligned to 8 XCDs
#define SBW 6250      // super-bin width
#define NBK (NR*NSB)  // 4000 buckets
#define NBE 256       // edge-pass blocks (k_edge / k_mkrec)
#define EPB (NE/NBE)  // 3125 edges per block
#define NTILE 3125    // 16-row GEMM tiles (50000/16 exactly)

typedef __attribute__((ext_vector_type(8))) __bf16 bf16x8;
typedef __attribute__((ext_vector_type(4))) float f32x4;

// ---- workspace layout (bytes, 16B aligned), total ~63.4 MiB ----
#define OFF_XH     0UL            // [NN][128] bf16
#define OFF_XT     12800000UL     // [NN][128] bf16
#define OFF_SP     25600000UL     // [NN] float4
#define OFF_DP     26400000UL     // [NN] float4
#define OFF_SUMS   27200000UL     // [NR*4] f32 (8000 B)
#define OFF_HISTH  27208000UL     // [NBK] u32 totals (16000 B)
#define OFF_HISTT  27224000UL     // [NBK] u32 totals (16000 B)
// zero region SUMS..HISTT = 40000 B = 10000 u32
#define OFF_INVS   27240000UL     // [NR*4] f32
#define OFF_BASEH  27248000UL     // [NBK+1] u32 (16016 B)
#define OFF_BASET  27264016UL     // [NBK+1] u32
#define OFF_RECH   27312032UL     // [NE] uint2 (node, w1) 6.4 MB
#define OFF_RECT   33712032UL     // [NE] uint2 (node, w2) 6.4 MB
#define OFF_PART   40112032UL     // [NBK][128] f32 partials (2.048 MB)
#define OFF_AH     42160032UL     // [256] f32
#define OFF_AT     42161056UL     // [256] f32
#define OFF_FLAG   42162080UL     // u32
#define OFF_WHH    42162144UL     // [128][256] bf16, FRAGMENT order
#define OFF_WHL    42227680UL
#define OFF_WTH    42293216UL
#define OFF_WTL    42358752UL
#define OFF_HPBH   42424288UL     // [NBE][NBK] u32 per-block hist/offsets 4.096 MB
#define OFF_HPBT   46520288UL     // [NBE][NBK] u32                       4.096 MB
#define OFF_EX     50616288UL     // [NE] float4 exp-scores 12.8 MB
// end 63,416,288

__device__ __forceinline__ int clampi(int v, int hi) {  // [0, hi)
    v = v < 0 ? 0 : v;
    return v >= hi ? hi - 1 : v;
}

// Wave-replicated dtype sniff (see round-8 notes).
__device__ __forceinline__ int sniff_isbf(const unsigned* xe_raw) {
    int lane = threadIdx.x & 63;
    unsigned w = xe_raw[lane];
    unsigned ex = (w >> 7) & 0xFFu;
    bool hit = (ex >= 115u && ex <= 131u);
    return __popcll(__ballot(hit)) >= 32;
}

// block 0: flag + a_h/a_t convert. blocks 1..128: weight split -> FRAGMENT
// order (see k_gemm). blocks 129+: zero sums + histH + histT (10000 u32).
// Frag order: out index o = ((ct*8+ks)*64 + q*16 + c)*8 + e  holds
// w[ct*16+c][ks*32+q*8+e]  — so lane l=q*16+c of fragment (ct,ks) reads its
// 8 contiguous bf16 (col=l&15, k-seg=(l>>4)*8) as one 16B chunk, and a
// wave's fragment read is one contiguous 1KB load (or LDS stage is linear).
__global__ __launch_bounds__(256) void k_init(const unsigned* __restrict__ xe_raw,
                                              const void* __restrict__ ah_in, const void* __restrict__ at_in,
                                              const void* __restrict__ wh, const void* __restrict__ wt,
                                              unsigned* __restrict__ flag, float* __restrict__ ah32,
                                              float* __restrict__ at32,
                                              __bf16* __restrict__ whh, __bf16* __restrict__ whl,
                                              __bf16* __restrict__ wth, __bf16* __restrict__ wtl,
                                              unsigned* __restrict__ zero1) {
    int isbf = sniff_isbf(xe_raw);
    int t = threadIdx.x;
    if (blockIdx.x == 0) {
        if (t == 0) flag[0] = (unsigned)isbf;
        ah32[t] = isbf ? __bfloat162float(((const __hip_bfloat16*)ah_in)[t]) : ((const float*)ah_in)[t];
        at32[t] = isbf ? __bfloat162float(((const __hip_bfloat16*)at_in)[t]) : ((const float*)at_in)[t];
    } else if (blockIdx.x <= 128) {
        int o = (blockIdx.x - 1) * 256 + t;   // [0, 32768) frag-order output idx
        int e = o & 7, c = (o >> 3) & 15, q = (o >> 7) & 3, ks = (o >> 9) & 7, ct = o >> 12;
        int i = (ct * 16 + c) * KEH + ks * 32 + q * 8 + e;   // row-major source
        if (isbf) {
            whh[o] = ((const __bf16*)wh)[i]; whl[o] = (__bf16)0.f;
            wth[o] = ((const __bf16*)wt)[i]; wtl[o] = (__bf16)0.f;
        } else {
            float a = ((const float*)wh)[i];
            float b = ((const float*)wt)[i];
            __bf16 ah_ = (__bf16)a, bh_ = (__bf16)b;
            whh[o] = ah_; whl[o] = (__bf16)(a - (float)ah_);
            wth[o] = bh_; wtl[o] = (__bf16)(b - (float)bh_);
        }
    } else {
        int stride = (gridDim.x - 129) * 256;
        for (int i = (blockIdx.x - 129) * 256 + t; i < 10000; i += stride) zero1[i] = 0u;
    }
}

// Split-phase GEMM + fused per-node scores.
// 782 blocks x 512 thr (8 waves); phase = bid&1 (0=H->xh, 1=T->xt);
// tile = (bid>>1)*8 + wave. Each block stages its phase's HI weight matrix
// (64 KB, linear copy — k_init wrote fragment order) into LDS once; each
// wave then does one 16-row tile: 8 A-frag loads from HBM, 64 iters of
// {1 ds_read_b128 (hi) [+1 L2 global load (lo) +3 MFMAs on fp32 path |
// +1 MFMA on bf16 path]}, then epilogue: xh/xt stores + 4 score
// dot-products/row via 16-lane shfl_xor, half-written to sp/dp (phases
// write disjoint float2 halves).
// 64 KB LDS + VGPR<=128 (launch_bounds 512,4) -> 2 blocks/CU resident:
// next block's staging/A-loads overlap this block's MFMA stream.
__global__ __launch_bounds__(512, 4) void k_gemm(const void* __restrict__ xe,
                                              const unsigned* __restrict__ flag,
                                              const __bf16* __restrict__ whh, const __bf16* __restrict__ whl,
                                              const __bf16* __restrict__ wth, const __bf16* __restrict__ wtl,
                                              const float* __restrict__ ah, const float* __restrict__ at,
                                              __hip_bfloat16* __restrict__ xh, __hip_bfloat16* __restrict__ xt,
                                              float2* __restrict__ sp2, float2* __restrict__ dp2) {
    __shared__ uint4 lb[4096];    // 64 KiB: this phase's HI matrix, frag order
    const int t = threadIdx.x, lane = t & 63, wave = t >> 6;
    const int l16 = lane & 15, quad = lane >> 4;
    const int ph = blockIdx.x & 1;
    const int tile = (int)(blockIdx.x >> 1) * 8 + wave;
    const int isbf = (int)flag[0];
    const __bf16* wfh = ph ? wth : whh;
    const __bf16* wfl = ph ? wtl : whl;

    {   // linear 64 KB stage: 512 thr x 8 x 16B
        const uint4* wsrc = (const uint4*)wfh;
        #pragma unroll
        for (int i = 0; i < 8; ++i) lb[i * 512 + t] = wsrc[i * 512 + t];
    }
    __syncthreads();
    if (tile >= NTILE) return;                 // only tail waves of last block
    const int row = tile * 16 + l16;           // this lane's A row

    f32x4 acc[8];
    #pragma unroll
    for (int ct = 0; ct < 8; ++ct) acc[ct] = (f32x4){0.f, 0.f, 0.f, 0.f};

    if (isbf) {
        const __bf16* xb = (const __bf16*)xe + (size_t)row * KEH;
        bf16x8 a[8];
        #pragma unroll
        for (int ks = 0; ks < 8; ++ks)
            a[ks] = *(const bf16x8*)(xb + ks * 32 + quad * 8);
        #pragma unroll
        for (int ks = 0; ks < 8; ++ks)
            #pragma unroll
            for (int ct = 0; ct < 8; ++ct)
                acc[ct] = __builtin_amdgcn_mfma_f32_16x16x32_bf16(
                    a[ks], *(const bf16x8*)&lb[(ct * 8 + ks) * 64 + lane], acc[ct], 0, 0, 0);
    } else {
        // fp32 hot path: error-compensated bf16 split; hi from LDS, lo
        // streamed from L2 (frag order, independent -> prefetchable).
        const float* xf = (const float*)xe + (size_t)row * KEH;
        bf16x8 ahi[8], alo[8];
        #pragma unroll
        for (int ks = 0; ks < 8; ++ks) {
            const float* p = xf + ks * 32 + quad * 8;
            float4 u0 = *(const float4*)p, u1 = *(const float4*)(p + 4);
            float v[8] = {u0.x,u0.y,u0.z,u0.w,u1.x,u1.y,u1.z,u1.w};
            #pragma unroll
            for (int jj = 0; jj < 8; ++jj) {
                __bf16 hi = (__bf16)v[jj];
                ahi[ks][jj] = hi;
                alo[ks][jj] = (__bf16)(v[jj] - (float)hi);
            }
        }
        #pragma unroll
        for (int ks = 0; ks < 8; ++ks)
            #pragma unroll
            for (int ct = 0; ct < 8; ++ct) {
                int fi = (ct * 8 + ks) * 64 + lane;
                bf16x8 bh = *(const bf16x8*)&lb[fi];
                bf16x8 bl = *(const bf16x8*)(wfl + ((size_t)fi << 3));
                acc[ct] = __builtin_amdgcn_mfma_f32_16x16x32_bf16(ahi[ks], bh, acc[ct], 0, 0, 0);
                acc[ct] = __builtin_amdgcn_mfma_f32_16x16x32_bf16(alo[ks], bh, acc[ct], 0, 0, 0);
                acc[ct] = __builtin_amdgcn_mfma_f32_16x16x32_bf16(ahi[ks], bl, acc[ct], 0, 0, 0);
            }
    }

    // ---- epilogue: store projected rows + fused scores ----
    __hip_bfloat16* out = ph ? xt : xh;
    float s0[4] = {0.f,0.f,0.f,0.f}, s1[4] = {0.f,0.f,0.f,0.f};
    float s2[4] = {0.f,0.f,0.f,0.f}, s3[4] = {0.f,0.f,0.f,0.f};
    #pragma unroll
    for (int ct = 0; ct < 8; ++ct) {
        int c = ct * 16 + l16;
        float va0 = ah[c], va1 = ah[128 + c];
        float vb0 = at[c], vb1 = at[128 + c];
        #pragma unroll
        for (int jj = 0; jj < 4; ++jj) {
            float v = acc[ct][jj];
            s0[jj] = fmaf(v, va0, s0[jj]);
            s1[jj] = fmaf(v, va1, s1[jj]);
            s2[jj] = fmaf(v, vb0, s2[jj]);
            s3[jj] = fmaf(v, vb1, s3[jj]);
            out[(size_t)(tile * 16 + quad * 4 + jj) * KRH + c] = __float2bfloat16(v);
        }
    }
    #pragma unroll
    for (int off = 8; off; off >>= 1)
        #pragma unroll
        for (int jj = 0; jj < 4; ++jj) {
            s0[jj] += __shfl_xor(s0[jj], off);
            s1[jj] += __shfl_xor(s1[jj], off);
            s2[jj] += __shfl_xor(s2[jj], off);
            s3[jj] += __shfl_xor(s3[jj], off);
        }
    if (l16 == 0) {
        // sp = (s_hh0, s_hh1, s_th0, s_th1); dp = (s_tt0, s_tt1, s_ht0, s_ht1)
        #pragma unroll
        for (int jj = 0; jj < 4; ++jj) {
            int n = tile * 16 + quad * 4 + jj;
            if (ph == 0) {
                sp2[n * 2 + 0] = make_float2(s0[jj], s1[jj]);   // s_hh
                dp2[n * 2 + 1] = make_float2(s2[jj], s3[jj]);   // s_ht
            } else {
                sp2[n * 2 + 1] = make_float2(s0[jj], s1[jj]);   // s_th
                dp2[n * 2 + 0] = make_float2(s2[jj], s3[jj]);   // s_tt
            }
        }
    }
}

__device__ __forceinline__ float eexp(float x) {
    x = x > 0.f ? x : 0.01f * x;
    x = fminf(x, 50.f);
    return __expf(x);
}

// Per edge (contiguous 3125-edge range per block, 1024 thr = 16 waves/CU):
// 4 exp scores -> ex4 store + LDS segment sums + (rel,sbin) histograms ->
// global totals (atomic) AND this block's private hpb row (non-atomic).
__global__ __launch_bounds__(1024) void k_edge(const int* __restrict__ src, const int* __restrict__ dst,
                                               const int* __restrict__ rel,
                                               const float4* __restrict__ sp, const float4* __restrict__ dp,
                                               float* __restrict__ sums,
                                               unsigned* __restrict__ histH, unsigned* __restrict__ histT,
                                               unsigned* __restrict__ hpbH, unsigned* __restrict__ hpbT,
                                               float4* __restrict__ ex4) {
    __shared__ float ls[NR * 4];
    __shared__ unsigned lhH[NBK], lhT[NBK];
    int t = threadIdx.x;
    for (int i = t; i < NR * 4; i += 1024) ls[i] = 0.f;
    for (int i = t; i < NBK; i += 1024) { lhH[i] = 0u; lhT[i] = 0u; }
    __syncthreads();
    unsigned lo = blockIdx.x * EPB, hi = lo + EPB;
    for (unsigned e = lo + t; e < hi; e += 1024) {
        int s = clampi(src[e], NN), d = clampi(dst[e], NN), r = clampi(rel[e], NR);
        float4 a = sp[s], b = dp[d];
        float4 ex;
        ex.x = eexp(a.x + b.x); ex.y = eexp(a.y + b.y);
        ex.z = eexp(a.z + b.z); ex.w = eexp(a.w + b.w);
        ex4[e] = ex;
        atomicAdd(&ls[r*4+0], ex.x);
        atomicAdd(&ls[r*4+1], ex.y);
        atomicAdd(&ls[r*4+2], ex.z);
        atomicAdd(&ls[r*4+3], ex.w);
        atomicAdd(&lhH[r * NSB + s / SBW], 1u);
        atomicAdd(&lhT[r * NSB + d / SBW], 1u);
    }
    __syncthreads();
    for (int i = t; i < NR * 4; i += 1024)
        if (ls[i] != 0.f) atomicAdd(&sums[i], ls[i]);
    size_t row = (size_t)blockIdx.x * NBK;
    for (int i = t; i < NBK; i += 1024) {
        unsigned cH = lhH[i], cT = lhT[i];
        hpbH[row + i] = cH;
        hpbT[row + i] = cT;
        if (cH) atomicAdd(&histH[i], cH);
        if (cT) atomicAdd(&histT[i], cT);
    }
}

// Scan both 4000-bin total histograms -> bucket bases; invs = 1/(sums+eps).
__global__ __launch_bounds__(1024) void k_scan2(const unsigned* __restrict__ histH,
                                                const unsigned* __restrict__ histT,
                                                const float* __restrict__ sums,
                                                unsigned* __restrict__ baseH, unsigned* __restrict__ baseT,
                                                float* __restrict__ invs) {
    __shared__ unsigned sc[1024];
    int t = threadIdx.x;
    for (int pass = 0; pass < 2; ++pass) {
        const unsigned* h = pass ? histT : histH;
        unsigned* base = pass ? baseT : baseH;
        int j0 = t * 4;
        unsigned v[4], s = 0;
        for (int k = 0; k < 4; ++k) { v[k] = (j0 + k < NBK) ? h[j0 + k] : 0u; s += v[k]; }
        sc[t] = s;
        __syncthreads();
        for (int off = 1; off < 1024; off <<= 1) {
            unsigned add = (t >= off) ? sc[t - off] : 0u;
            __syncthreads();
            sc[t] += add;
            __syncthreads();
        }
        unsigned run = sc[t] - s;
        for (int k = 0; k < 4; ++k) {
            if (j0 + k < NBK) { base[j0 + k] = run; run += v[k]; }
        }
        if (t == 1023) base[NBK] = sc[1023];
        __syncthreads();
    }
    for (int i = t; i < NR * 4; i += 1024) invs[i] = 1.f / (sums[i] + 1e-16f);
}

// Column scan: per (pass,bin), exclusive-scan the NBE per-block counts and add
// the bucket base -> hpb becomes each block's exact write offset. No atomics.
__global__ __launch_bounds__(NBE) void k_colscan(unsigned* __restrict__ hpbH, unsigned* __restrict__ hpbT,
                                                 const unsigned* __restrict__ baseH,
                                                 const unsigned* __restrict__ baseT) {
    __shared__ unsigned sc[NBE];
    int b = blockIdx.x;              // [0, 2*NBK)
    int pass = b >= NBK;
    int bin = pass ? b - NBK : b;
    unsigned* h = pass ? hpbT : hpbH;
    unsigned basev = (pass ? baseT : baseH)[bin];
    int t = threadIdx.x;
    unsigned v = h[(size_t)t * NBK + bin];
    sc[t] = v;
    __syncthreads();
    for (int off = 1; off < NBE; off <<= 1) {
        unsigned add = (t >= off) ? sc[t - off] : 0u;
        __syncthreads();
        sc[t] += add;
        __syncthreads();
    }
    h[(size_t)t * NBK + bin] = basev + sc[t] - v;
}

// Single-pass scatter (1024 thr): weights from streamed ex4 (no gathers, no
// exp); LDS cursors from precomputed per-block offsets.
__global__ __launch_bounds__(1024) void k_mkrec(const int* __restrict__ src, const int* __restrict__ dst,
                                                const int* __restrict__ rel,
                                                const float4* __restrict__ ex4,
                                                const float4* __restrict__ invs4,
                                                const unsigned* __restrict__ hpbH, const unsigned* __restrict__ hpbT,
                                                uint2* __restrict__ recH, uint2* __restrict__ recT) {
    __shared__ unsigned lcH[NBK], lcT[NBK];
    int t = threadIdx.x;
    size_t row = (size_t)blockIdx.x * NBK;
    for (int i = t; i < NBK; i += 1024) { lcH[i] = hpbH[row + i]; lcT[i] = hpbT[row + i]; }
    __syncthreads();
    unsigned lo = blockIdx.x * EPB, hi = lo + EPB;
    for (unsigned e = lo + t; e < hi; e += 1024) {
        int s = clampi(src[e], NN), d = clampi(dst[e], NN), r = clampi(rel[e], NR);
        float4 ex = ex4[e];
        float4 iv = invs4[r];
        float w1 = ex.x * iv.x + ex.y * iv.y;
        float w2 = ex.z * iv.z + ex.w * iv.w;
        unsigned pH = atomicAdd(&lcH[r * NSB + s / SBW], 1u);
        unsigned pT = atomicAdd(&lcT[r * NSB + d / SBW], 1u);
        if (pH < NE) recH[pH] = make_uint2((unsigned)s, __float_as_uint(w1));
        if (pT < NE) recT[pT] = make_uint2((unsigned)d, __float_as_uint(w2));
    }
}

// One block per (rel,sbin) bucket. Chunked: stage 256 recs into LDS in one
// coalesced burst, then each wave runs an 8-wide gather unroll with rec reads
// from LDS — rec-load latency off the critical path, 8 gathers in flight.
__global__ __launch_bounds__(256) void k_accR(const uint2* __restrict__ recH, const uint2* __restrict__ recT,
                                              const unsigned* __restrict__ baseH, const unsigned* __restrict__ baseT,
                                              const __hip_bfloat16* __restrict__ xh,
                                              const __hip_bfloat16* __restrict__ xt,
                                              float* __restrict__ part) {
    __shared__ float red[4][128];
    __shared__ uint2 lrec[256];
    int b = blockIdx.x;
    int t = threadIdx.x, lane = t & 63, wv = t >> 6;
    int c2 = lane * 2;
    float ax = 0.f, ay = 0.f;
    for (int pass = 0; pass < 2; ++pass) {
        const uint2* rec = pass ? recT : recH;
        const unsigned* base = pass ? baseT : baseH;
        const unsigned short* xs = (const unsigned short*)(pass ? xt : xh);
        unsigned b0 = base[b];
        unsigned cnt = base[b + 1] - b0;
        if (cnt > NE) cnt = 0;        // poison guard
        for (unsigned cb = 0; cb < cnt; cb += 256u) {
            unsigned cn = cnt - cb; if (cn > 256u) cn = 256u;
            __syncthreads();                       // prior chunk readers done
            if ((unsigned)t < cn) lrec[t] = rec[b0 + cb + t];
            __syncthreads();
            for (unsigned j = (unsigned)wv; j < cn; j += 32) {
                unsigned nd[8]; float w[8];
                #pragma unroll
                for (int k = 0; k < 8; ++k) {
                    unsigned jj = j + 4u * k;
                    bool m = jj < cn;
                    uint2 v = lrec[m ? jj : j];
                    nd[k] = v.x < NN ? v.x : 0u;
                    w[k] = m ? __uint_as_float(v.y) : 0.f;
                }
                unsigned u[8];
                #pragma unroll
                for (int k = 0; k < 8; ++k)
                    u[k] = *(const unsigned*)(xs + (size_t)nd[k] * KRH + c2);
                #pragma unroll
                for (int k = 0; k < 8; ++k) {
                    ax = fmaf(w[k], __uint_as_float(u[k] << 16), ax);
                    ay = fmaf(w[k], __uint_as_float(u[k] & 0xffff0000u), ay);
                }
            }
        }
    }
    __syncthreads();
    red[wv][c2] = ax; red[wv][c2 + 1] = ay;
    __syncthreads();
    if (wv == 0) {
        float vx = red[0][c2] + red[1][c2] + red[2][c2] + red[3][c2];
        float vy = red[0][c2+1] + red[1][c2+1] + red[2][c2+1] + red[3][c2+1];
        *(float2*)(&part[(size_t)b * KRH + c2]) = make_float2(vx, vy);
    }
}

// out[r][c] = 0.25 * sum_sbin part[r*8+sbin][c]; dtype follows input.
__global__ __launch_bounds__(256) void k_out(const float* __restrict__ part,
                                             const unsigned* __restrict__ flag, void* __restrict__ out) {
    int i = blockIdx.x * 256 + threadIdx.x;
    if (i < NR * KRH) {
        int r = i >> 7, c = i & 127;
        float v = 0.f;
        for (int s = 0; s < NSB; ++s) v += part[(size_t)(r * NSB + s) * KRH + c];
        v *= 0.25f;                   // / num_heads(2) / 2
        if (!isfinite(v)) v = 0.f;
        if (flag[0]) ((__hip_bfloat16*)out)[i] = __float2bfloat16(v);
        else         ((float*)out)[i] = v;
    }
}

extern "C" void kernel_launch(void* const* d_in, const int* in_sizes, int n_in,
                              void* d_out, int out_size, void* d_ws, size_t ws_size,
                              hipStream_t stream) {
    const void* xe  = d_in[0];
    const int* eidx = (const int*)d_in[1];
    const int* rel  = (const int*)d_in[2];
    const void* wh  = d_in[3];
    const void* wt  = d_in[4];
    const void* ahp = d_in[5];
    const void* atp = d_in[6];

    const int* src = eidx;
    const int* dst = eidx + NE;

    char* ws = (char*)d_ws;
    __hip_bfloat16* xh = (__hip_bfloat16*)(ws + OFF_XH);
    __hip_bfloat16* xt = (__hip_bfloat16*)(ws + OFF_XT);
    float4*   sp     = (float4*)(ws + OFF_SP);
    float4*   dp     = (float4*)(ws + OFF_DP);
    float*    sums   = (float*)(ws + OFF_SUMS);
    unsigned* histH  = (unsigned*)(ws + OFF_HISTH);
    unsigned* histT  = (unsigned*)(ws + OFF_HISTT);
    float*    invs   = (float*)(ws + OFF_INVS);
    unsigned* baseH  = (unsigned*)(ws + OFF_BASEH);
    unsigned* baseT  = (unsigned*)(ws + OFF_BASET);
    uint2*    recH   = (uint2*)(ws + OFF_RECH);
    uint2*    recT   = (uint2*)(ws + OFF_RECT);
    float*    partp  = (float*)(ws + OFF_PART);
    float*    ah32   = (float*)(ws + OFF_AH);
    float*    at32   = (float*)(ws + OFF_AT);
    unsigned* flag   = (unsigned*)(ws + OFF_FLAG);
    __bf16*   whh    = (__bf16*)(ws + OFF_WHH);
    __bf16*   whl    = (__bf16*)(ws + OFF_WHL);
    __bf16*   wth    = (__bf16*)(ws + OFF_WTH);
    __bf16*   wtl    = (__bf16*)(ws + OFF_WTL);
    unsigned* hpbH   = (unsigned*)(ws + OFF_HPBH);
    unsigned* hpbT   = (unsigned*)(ws + OFF_HPBT);
    float4*   ex4    = (float4*)(ws + OFF_EX);

    k_init<<<161, 256, 0, stream>>>((const unsigned*)xe, ahp, atp, wh, wt, flag, ah32, at32,
                                     whh, whl, wth, wtl, (unsigned*)(ws + OFF_SUMS));
    k_gemm<<<2 * ((NTILE + 7) / 8), 512, 0, stream>>>(xe, flag, whh, whl, wth, wtl, ah32, at32,
                                                      xh, xt, (float2*)sp, (float2*)dp);
    k_edge<<<NBE, 1024, 0, stream>>>(src, dst, rel, sp, dp, sums, histH, histT, hpbH, hpbT, ex4);
    k_scan2<<<1, 1024, 0, stream>>>(histH, histT, sums, baseH, baseT, invs);
    k_colscan<<<2 * NBK, NBE, 0, stream>>>(hpbH, hpbT, baseH, baseT);
    k_mkrec<<<NBE, 1024, 0, stream>>>(src, dst, rel, ex4, (const float4*)invs, hpbH, hpbT, recH, recT);
    k_accR<<<NBK, 256, 0, stream>>>(recH, recT, baseH, baseT, xh, xt, partp);
    k_out<<<(NR * KRH + 255) / 256, 256, 0, stream>>>(partp, flag, d_out);
}